// Round 10
// baseline (92519.263 us; speedup 1.0000x reference)
//
#include <hip/hip_runtime.h>
#include <hip/hip_bf16.h>

#define H 500
#define D_IN 512
#define D_OUT 100
#define STEPS 49
#define NWG 4
#define RPW 125   // rows per worker block
#define NBLK 44   // 4 workers + 40 producers (pigeonhole: some XCD gets >=6)

typedef _Float16 h2_t __attribute__((ext_vector_type(2)));

#if defined(__has_builtin)
#if __has_builtin(__builtin_amdgcn_fdot2)
#define HAVE_FDOT2 1
#endif
#endif

__device__ __forceinline__ float fdot2f(h2_t a, h2_t b, float c) {
#ifdef HAVE_FDOT2
    return __builtin_amdgcn_fdot2(a, b, c, false);
#else
    return c + (float)a[0] * (float)b[0] + (float)a[1] * (float)b[1];
#endif
}
__device__ __forceinline__ h2_t bch2(unsigned u) { return __builtin_bit_cast(h2_t, u); }
__device__ __forceinline__ unsigned pk(float a, float b) {
    return __builtin_bit_cast(unsigned, h2_t{(_Float16)a, (_Float16)b});
}
__device__ __forceinline__ float tanh_fast(float x) {
    const float e = __expf(2.f * x);
    return 1.f - 2.f / (e + 1.f);
}

// ---------------- fused cooperative kernel ----------------
// Election: block reads its XCC_ID; per-XCD tickets in elect[0..7]; 4th block
// on an XCD claims elect[8] (winner = xcd+1). Workers = tickets 0..3 on the
// winning XCD (one shared L2!). All others become xproj producers via elect[9].
//
// Workers (4 blocks x 512 thr): WG g owns rows [125g,125g+125), weights f16 in
// LDS (131 KB). h exchange through hbuf[50][512] (sentinel 0xFFFFFFFF = -NaN,
// unreachable by tanh/fma arithmetic): writer = workgroup-scope atomic swap
// (executes at the shared XCD L2, ~200cy) + agent-scope backup swap (MALL);
// pollers = workgroup-scope fetch_or(0) spins with agent-scope fallback after
// 20K spins (guaranteed progress via the r9-proven agent path -> no hang).
//
// Producers: 13 rows each of xproj[t*512+r] = b_ih+b_hh+sum_d seq[t][d]*W_ih[r][d],
// written with agent-scope atomic stores into sentinel-initialized xproj;
// worker q==0 threads poll their row's word at agent scope each step.
__global__ void __launch_bounds__(512, 1)
k2_fused(const float* __restrict__ hidden0, const float* __restrict__ W_hh,
         const float* __restrict__ x, const float* __restrict__ W_ih,
         const float* __restrict__ b_ih, const float* __restrict__ b_hh,
         unsigned* elect, float* xproj, float* hbuf, float* __restrict__ Hs) {
    __shared__ uint4 wq[16][512];                 // 131072 B  worker weights
    __shared__ _Float16 hlds[2][512];             // 2048 B
    __shared__ float pbuf[NWG][128];              // 2048 B
    __shared__ unsigned role_s[2];

    const int tid = threadIdx.x;

    if (tid == 0) {
        unsigned xcd;
        asm volatile("s_getreg_b32 %0, hwreg(HW_REG_XCC_ID)" : "=s"(xcd));
        xcd &= 7u;
        const unsigned ticket = __hip_atomic_fetch_add(&elect[xcd], 1u,
                                    __ATOMIC_RELAXED, __HIP_MEMORY_SCOPE_AGENT);
        if (ticket == 3u) {
            unsigned exp0 = 0u;
            __hip_atomic_compare_exchange_strong(&elect[8], &exp0, xcd + 1u,
                __ATOMIC_RELAXED, __ATOMIC_RELAXED, __HIP_MEMORY_SCOPE_AGENT);
        }
        unsigned win;
        do {
            win = __hip_atomic_load(&elect[8], __ATOMIC_RELAXED, __HIP_MEMORY_SCOPE_AGENT);
        } while (win == 0u);
        if (win == xcd + 1u && ticket < 4u) {
            role_s[0] = 1u; role_s[1] = ticket;
        } else {
            role_s[0] = 0u;
            role_s[1] = __hip_atomic_fetch_add(&elect[9], 1u,
                            __ATOMIC_RELAXED, __HIP_MEMORY_SCOPE_AGENT);
        }
    }
    __syncthreads();

    if (role_s[0] == 0u) {
        // ---------------- producer: xproj rows [13p, 13p+13) ----------------
        const int p = (int)role_s[1];
        const int base = p * 13;
        const int wv = tid >> 6, lane = tid & 63;
        for (int i = wv; i < 13; i += 8) {
            const int r = base + i;
            if (r >= H) break;
            float wr8[8];
#pragma unroll
            for (int k = 0; k < 8; k++) wr8[k] = W_ih[r * D_IN + k * 64 + lane];
            float pv[STEPS];
#pragma unroll
            for (int t = 0; t < STEPS; t++) pv[t] = 0.f;
#pragma unroll
            for (int k = 0; k < 8; k++) {
                const float* xr = x + (size_t)(k * 64 + lane) * STEPS;
#pragma unroll
                for (int t = 0; t < STEPS; t++) pv[t] = fmaf(wr8[k], xr[t], pv[t]);
            }
#pragma unroll
            for (int t = 0; t < STEPS; t++) {
                float v = pv[t];
                v += __shfl_xor(v, 32); v += __shfl_xor(v, 16); v += __shfl_xor(v, 8);
                v += __shfl_xor(v, 4);  v += __shfl_xor(v, 2);  v += __shfl_xor(v, 1);
                pv[t] = v;
            }
            if (lane == 0) {
                const float b = b_ih[r] + b_hh[r];
                for (int t = 0; t < STEPS; t++)
                    __hip_atomic_store(&xproj[t * 512 + r], pv[t] + b,
                                       __ATOMIC_RELAXED, __HIP_MEMORY_SCOPE_AGENT);
            }
        }
        return;
    }

    // ---------------- worker ----------------
    const int g = (int)role_s[1];                 // 0..3
    const int q = tid >> 7, r = tid & 127;
    const int row = g * RPW + r;                  // valid when r < RPW

    // one-time: this WG's weight slice -> LDS (f32 -> f16)
#pragma unroll
    for (int c = 0; c < 16; c++) {
        uint4 u = uint4{0u, 0u, 0u, 0u};
        if (r < RPW) {
            const float* rowp = W_hh + (size_t)row * H;
            const int c0 = 128 * q + 8 * c;
            if (c0 + 7 < H) {
                const float4 f0 = *(const float4*)(rowp + c0);
                const float4 f1 = *(const float4*)(rowp + c0 + 4);
                u.x = pk(f0.x, f0.y); u.y = pk(f0.z, f0.w);
                u.z = pk(f1.x, f1.y); u.w = pk(f1.z, f1.w);
            } else {
                float f[8];
#pragma unroll
                for (int e = 0; e < 8; e++) {
                    const int col = c0 + e;
                    f[e] = (col < H) ? rowp[col] : 0.f;
                }
                u.x = pk(f[0], f[1]); u.y = pk(f[2], f[3]);
                u.z = pk(f[4], f[5]); u.w = pk(f[6], f[7]);
            }
        }
        wq[c][tid] = u;
    }
    hlds[0][tid] = (tid < H) ? (_Float16)hidden0[tid] : (_Float16)0.f;
    hlds[1][tid] = (_Float16)0.f;
    __syncthreads();

#pragma unroll 1
    for (int t = 0; t < STEPS; ++t) {
        const int cur = t & 1, nxt = cur ^ 1;

        const uint4* hc = (const uint4*)&hlds[cur][0] + 16 * q;  // broadcast
        float s0 = 0.f, s1 = 0.f, s2 = 0.f, s3 = 0.f;
#pragma unroll
        for (int c = 0; c < 16; c++) {
            const uint4 wv_ = wq[c][tid];
            const uint4 hb = hc[c];
            s0 = fdot2f(bch2(wv_.x), bch2(hb.x), s0);
            s1 = fdot2f(bch2(wv_.y), bch2(hb.y), s1);
            s2 = fdot2f(bch2(wv_.z), bch2(hb.z), s2);
            s3 = fdot2f(bch2(wv_.w), bch2(hb.w), s3);
        }
        if (q != 0) pbuf[q][r] = (s0 + s1) + (s2 + s3);

        float xp = 0.f;
        if (q == 0 && r < RPW) {                  // poll xproj (agent, MALL)
            unsigned xb;
            do {
                xb = __builtin_bit_cast(unsigned,
                        __hip_atomic_load(&xproj[t * 512 + row],
                                          __ATOMIC_RELAXED, __HIP_MEMORY_SCOPE_AGENT));
            } while (xb == 0xFFFFFFFFu);
            xp = __builtin_bit_cast(float, xb);
        }
        __syncthreads();

        if (q == 0 && r < RPW) {
            const float tot = (s0 + s1) + (s2 + s3)
                            + pbuf[1][r] + pbuf[2][r] + pbuf[3][r] + xp;
            const float hv = tanh_fast(tot);
            Hs[t * 512 + row] = hv;
            const unsigned hb_ = __builtin_bit_cast(unsigned, hv);
            unsigned* pw = (unsigned*)&hbuf[(t + 1) * 512 + row];
            __hip_atomic_exchange(pw, hb_, __ATOMIC_RELAXED,
                                  __HIP_MEMORY_SCOPE_WORKGROUP);   // shared-L2 fast path
            __hip_atomic_exchange(pw, hb_, __ATOMIC_RELAXED,
                                  __HIP_MEMORY_SCOPE_AGENT);       // MALL backup
            hlds[nxt][row] = (_Float16)hv;
        }
        const bool own_word = (tid >= g * RPW) && (tid < g * RPW + RPW);
        if ((t + 1 < STEPS) && (tid < H) && !own_word) {
            unsigned* pw = (unsigned*)&hbuf[(t + 1) * 512 + tid];
            unsigned bits_;
            int spins = 0;
            for (;;) {
                bits_ = __hip_atomic_fetch_or(pw, 0u, __ATOMIC_RELAXED,
                                              __HIP_MEMORY_SCOPE_WORKGROUP);  // L2 RMW
                if (bits_ != 0xFFFFFFFFu) break;
                if (++spins > 20000) {
                    bits_ = __hip_atomic_fetch_or(pw, 0u, __ATOMIC_RELAXED,
                                                  __HIP_MEMORY_SCOPE_AGENT);  // fallback
                    if (bits_ != 0xFFFFFFFFu) break;
                }
            }
            hlds[nxt][tid] = (_Float16)__builtin_bit_cast(float, bits_);
        }
        __syncthreads();
    }
}

// ---------------- K3: out[t][o] = tanh(b_out[o] + sum_c Hs[t][c]*W_out[o][c])
__global__ void k3_out(const float* __restrict__ Hs, const float* __restrict__ W_out,
                       const float* __restrict__ b_out, float* __restrict__ out) {
    const int t = blockIdx.x, o = threadIdx.x;
    if (o < D_OUT) {
        const float4* wr = (const float4*)(W_out + o * H);
        const float4* hr = (const float4*)(Hs + t * 512);
        float acc = b_out[o];
#pragma unroll 5
        for (int i = 0; i < 125; i++) {
            const float4 wv = wr[i];
            const float4 hv = hr[i];
            acc = fmaf(wv.x, hv.x, acc);
            acc = fmaf(wv.y, hv.y, acc);
            acc = fmaf(wv.z, hv.z, acc);
            acc = fmaf(wv.w, hv.w, acc);
        }
        out[t * D_OUT + o] = tanh_fast(acc);
    }
}

extern "C" void kernel_launch(void* const* d_in, const int* in_sizes, int n_in,
                              void* d_out, int out_size, void* d_ws, size_t ws_size,
                              hipStream_t stream) {
    const float* x       = (const float*)d_in[0];
    const float* hidden0 = (const float*)d_in[1];
    const float* W_ih    = (const float*)d_in[2];
    const float* W_hh    = (const float*)d_in[3];
    const float* b_ih    = (const float*)d_in[4];
    const float* b_hh    = (const float*)d_in[5];
    const float* W_out   = (const float*)d_in[6];
    const float* b_out   = (const float*)d_in[7];
    float* out = (float*)d_out;

    char* ws = (char*)d_ws;
    unsigned* elect = (unsigned*)ws;               // 64 B     (zeroed each launch)
    float* hbuf  = (float*)(ws + 64);              // 50*512*4 = 102400 (sentinel)
    float* xproj = (float*)(ws + 64 + 102400);     // 49*512*4 = 100352 (sentinel)
    float* Hs    = (float*)(ws + 64 + 202752);     // 100352

    hipMemsetAsync(elect, 0, 64, stream);
    hipMemsetAsync(hbuf, 0xFF, 102400, stream);
    hipMemsetAsync(xproj, 0xFF, 100352, stream);
    k2_fused<<<NBLK, 512, 0, stream>>>(hidden0, W_hh, x, W_ih, b_ih, b_hh,
                                       elect, xproj, hbuf, Hs);
    k3_out<<<STEPS, 128, 0, stream>>>(Hs, W_out, b_out, out);
}

// Round 11
// 103.634 us; speedup vs baseline: 892.7532x; 892.7532x over previous
//
#include <hip/hip_runtime.h>
#include <hip/hip_bf16.h>

#define H 500
#define D_IN 512
#define D_OUT 100
#define STEPS 49
#define NWG 4
#define SENT 0xFFFFFFFFu

typedef _Float16 h2_t __attribute__((ext_vector_type(2)));

#if defined(__has_builtin)
#if __has_builtin(__builtin_amdgcn_fdot2)
#define HAVE_FDOT2 1
#endif
#endif

__device__ __forceinline__ float fdot2f(h2_t a, h2_t b, float c) {
#ifdef HAVE_FDOT2
    return __builtin_amdgcn_fdot2(a, b, c, false);
#else
    return c + (float)a[0] * (float)b[0] + (float)a[1] * (float)b[1];
#endif
}
__device__ __forceinline__ h2_t bch2(unsigned u) { return __builtin_bit_cast(h2_t, u); }
__device__ __forceinline__ unsigned pk(float a, float b) {
    return __builtin_bit_cast(unsigned, h2_t{(_Float16)a, (_Float16)b});
}
__device__ __forceinline__ float tanh_fast(float x) {
    const float e = __expf(2.f * x);
    return 1.f - 2.f / (e + 1.f);
}
__device__ __forceinline__ int clen(int g) { return (g < 3) ? 128 : (H - 384); }  // 116

// ---------------- K1: xproj[t*512+r] = b_ih[r]+b_hh[r]+sum_d seq[t][d]*W_ih[r][d]
// 125 blocks x 256 threads (4 rows/block, one per wave). seq[t][d] = x[d*49+t].
__global__ void k1_xproj(const float* __restrict__ x, const float* __restrict__ W_ih,
                         const float* __restrict__ b_ih, const float* __restrict__ b_hh,
                         float* __restrict__ xproj) {
    const int wv = threadIdx.x >> 6, lane = threadIdx.x & 63;
    const int r = blockIdx.x * 4 + wv;            // 0..499
    float wr[8];
#pragma unroll
    for (int k = 0; k < 8; k++) wr[k] = W_ih[r * D_IN + k * 64 + lane];
    float p[STEPS];
#pragma unroll
    for (int t = 0; t < STEPS; t++) p[t] = 0.f;
#pragma unroll
    for (int k = 0; k < 8; k++) {
        const float* xr = x + (size_t)(k * 64 + lane) * STEPS;
#pragma unroll
        for (int t = 0; t < STEPS; t++) p[t] = fmaf(wr[k], xr[t], p[t]);
    }
#pragma unroll
    for (int t = 0; t < STEPS; t++) {
        float v = p[t];
        v += __shfl_xor(v, 32); v += __shfl_xor(v, 16); v += __shfl_xor(v, 8);
        v += __shfl_xor(v, 4);  v += __shfl_xor(v, 2);  v += __shfl_xor(v, 1);
        p[t] = v;
    }
    if (lane == 0) {
        const float b = b_ih[r] + b_hh[r];
        for (int t = 0; t < STEPS; t++) xproj[t * 512 + r] = p[t] + b;
    }
}

// ---------------- K2: column-split dataflow scan. 4 WGs x 512 threads.
// WG g owns h-chunk g (rows/cols [128g, 128g+clen(g))) and the column slice
// W_hh[:, chunk_g] in LDS (f16, 131 KB). Per step: compute partials for the 3
// remote chunks from LOCAL h (send each immediately, agent-scope store), then
// own chunk, then poll 3 incoming partials (sentinel one-shot buffer), tanh,
// stage own h chunk locally. h is never broadcast; only partials cross WGs,
// and their MALL flight overlaps the rest of the compute.
// Thread map: rr = tid>>2 (row-in-chunk), sub = tid&3 (32-col quarter).
__global__ void __launch_bounds__(512, 1)
k2_scan(const float* __restrict__ hidden0, const float* __restrict__ W_hh,
        const float* __restrict__ xproj, float* part, float* __restrict__ Hs) {
    __shared__ uint4 wl[16 * 512];                  // 131072 B
    __shared__ __align__(16) _Float16 hch[2][128];  // 512 B

    const int g = blockIdx.x, tid = threadIdx.x;
    const int rr = tid >> 2, sub = tid & 3;
    const int myLen = clen(g);

    // ---- preamble: W_hh[:, 128g + 32sub .. +32) rows 128d+rr -> LDS (f16) ----
#pragma unroll
    for (int d = 0; d < 4; d++) {
        uint4 u[4] = {{0,0,0,0},{0,0,0,0},{0,0,0,0},{0,0,0,0}};
        if (rr < clen(d)) {
            const int row = 128 * d + rr;
            const float* rowp = W_hh + (size_t)row * H + 128 * g + 32 * sub;
            const int cmax = myLen - 32 * sub;      // valid cols: cc < cmax
            if (cmax >= 32) {                       // aligned fast path (16B)
#pragma unroll
                for (int q8 = 0; q8 < 4; q8++) {
                    const float4 f0 = *(const float4*)(rowp + 8 * q8);
                    const float4 f1 = *(const float4*)(rowp + 8 * q8 + 4);
                    u[q8].x = pk(f0.x, f0.y); u[q8].y = pk(f0.z, f0.w);
                    u[q8].z = pk(f1.x, f1.y); u[q8].w = pk(f1.z, f1.w);
                }
            } else {                                // boundary (g==3, sub==3)
                float f[32];
#pragma unroll
                for (int cc = 0; cc < 32; cc++) f[cc] = (cc < cmax) ? rowp[cc] : 0.f;
#pragma unroll
                for (int q8 = 0; q8 < 4; q8++) {
                    u[q8].x = pk(f[8*q8+0], f[8*q8+1]);
                    u[q8].y = pk(f[8*q8+2], f[8*q8+3]);
                    u[q8].z = pk(f[8*q8+4], f[8*q8+5]);
                    u[q8].w = pk(f[8*q8+6], f[8*q8+7]);
                }
            }
        }
#pragma unroll
        for (int c = 0; c < 4; c++) wl[(d * 4 + c) * 512 + tid] = u[c];
    }
    if (tid < 128) hch[0][tid] = (tid < myLen) ? (_Float16)hidden0[128 * g + tid]
                                               : (_Float16)0.f;
    else if (tid < 256) hch[1][tid - 128] = (_Float16)0.f;
    __syncthreads();

#pragma unroll 1
    for (int t = 0; t < STEPS; ++t) {
        const int cur = t & 1;
        float xp = 0.f;
        if (sub == 0 && rr < myLen) xp = xproj[t * 512 + 128 * g + rr];  // early

        const uint4* hc = (const uint4*)&hch[cur][0];
        uint4 hv4[4];
#pragma unroll
        for (int c = 0; c < 4; c++) hv4[c] = hc[sub * 4 + c];   // broadcast reads

        float own = 0.f;
#pragma unroll
        for (int k = 0; k < 4; k++) {
            const int d = (g + 1 + k) & 3;          // k=0..2 remote, k=3 own
            float s = 0.f;
#pragma unroll
            for (int c = 0; c < 4; c++) {
                const uint4 w = wl[(d * 4 + c) * 512 + tid];
                const uint4 hb = hv4[c];
                s = fdot2f(bch2(w.x), bch2(hb.x), s);
                s = fdot2f(bch2(w.y), bch2(hb.y), s);
                s = fdot2f(bch2(w.z), bch2(hb.z), s);
                s = fdot2f(bch2(w.w), bch2(hb.w), s);
            }
            s += __shfl_xor(s, 1);                  // reduce 4 col-quarters
            s += __shfl_xor(s, 2);
            if (k < 3) {
                if (sub == 0)                       // send ASAP (staggered)
                    __hip_atomic_store(&part[((t * 4 + d) * 4 + g) * 128 + rr], s,
                                       __ATOMIC_RELAXED, __HIP_MEMORY_SCOPE_AGENT);
            } else own = s;
        }

        if (sub == 0 && rr < myLen) {
            const int g1 = (g + 1) & 3, g2 = (g + 2) & 3, g3 = (g + 3) & 3;
            const float* pb = &part[(t * 4 + g) * 4 * 128];
            unsigned b1 = SENT, b2 = SENT, b3 = SENT;
            do {                                    // 3 pipelined MALL loads/iter
                if (b1 == SENT) b1 = __builtin_bit_cast(unsigned,
                    __hip_atomic_load(&pb[g1 * 128 + rr], __ATOMIC_RELAXED,
                                      __HIP_MEMORY_SCOPE_AGENT));
                if (b2 == SENT) b2 = __builtin_bit_cast(unsigned,
                    __hip_atomic_load(&pb[g2 * 128 + rr], __ATOMIC_RELAXED,
                                      __HIP_MEMORY_SCOPE_AGENT));
                if (b3 == SENT) b3 = __builtin_bit_cast(unsigned,
                    __hip_atomic_load(&pb[g3 * 128 + rr], __ATOMIC_RELAXED,
                                      __HIP_MEMORY_SCOPE_AGENT));
            } while (b1 == SENT || b2 == SENT || b3 == SENT);
            const float tot = own + __builtin_bit_cast(float, b1)
                                  + __builtin_bit_cast(float, b2)
                                  + __builtin_bit_cast(float, b3) + xp;
            const float hv = tanh_fast(tot);
            Hs[t * 512 + 128 * g + rr] = hv;
            hch[cur ^ 1][rr] = (_Float16)hv;        // pads (rr>=myLen) stay 0
        }
        __syncthreads();
    }
}

// ---------------- K3: out[t][o] = tanh(b_out[o] + sum_c Hs[t][c]*W_out[o][c])
__global__ void k3_out(const float* __restrict__ Hs, const float* __restrict__ W_out,
                       const float* __restrict__ b_out, float* __restrict__ out) {
    const int t = blockIdx.x, o = threadIdx.x;
    if (o < D_OUT) {
        const float4* wr = (const float4*)(W_out + o * H);
        const float4* hr = (const float4*)(Hs + t * 512);
        float acc = b_out[o];
#pragma unroll 5
        for (int i = 0; i < 125; i++) {
            const float4 wv = wr[i];
            const float4 hv = hr[i];
            acc = fmaf(wv.x, hv.x, acc);
            acc = fmaf(wv.y, hv.y, acc);
            acc = fmaf(wv.z, hv.z, acc);
            acc = fmaf(wv.w, hv.w, acc);
        }
        out[t * D_OUT + o] = tanh_fast(acc);
    }
}

extern "C" void kernel_launch(void* const* d_in, const int* in_sizes, int n_in,
                              void* d_out, int out_size, void* d_ws, size_t ws_size,
                              hipStream_t stream) {
    const float* x       = (const float*)d_in[0];
    const float* hidden0 = (const float*)d_in[1];
    const float* W_ih    = (const float*)d_in[2];
    const float* W_hh    = (const float*)d_in[3];
    const float* b_ih    = (const float*)d_in[4];
    const float* b_hh    = (const float*)d_in[5];
    const float* W_out   = (const float*)d_in[6];
    const float* b_out   = (const float*)d_in[7];
    float* out = (float*)d_out;

    char* ws = (char*)d_ws;
    float* part  = (float*)ws;                     // 49*4*4*128*4 = 401408 (sentinel)
    float* xproj = (float*)(ws + 401408);          // 49*512*4 = 100352
    float* Hs    = (float*)(ws + 501760);          // 100352   (total 602112)

    hipMemsetAsync(part, 0xFF, 401408, stream);    // one-shot sentinel init
    k1_xproj<<<125, 256, 0, stream>>>(x, W_ih, b_ih, b_hh, xproj);
    k2_scan<<<NWG, 512, 0, stream>>>(hidden0, W_hh, xproj, part, Hs);
    k3_out<<<STEPS, 128, 0, stream>>>(Hs, W_out, b_out, out);
}